// Round 2
// baseline (430.577 us; speedup 1.0000x reference)
//
#include <hip/hip_runtime.h>

typedef __bf16 bf16_t;
typedef __attribute__((ext_vector_type(8))) __bf16 bf16x8;
typedef __attribute__((ext_vector_type(4))) float floatx4;

#define MFMA16(a, b, c) __builtin_amdgcn_mfma_f32_16x16x32_bf16((a), (b), (c), 0, 0, 0)
// async global->LDS, 16B/lane: lane i's 16B lands at ldsbase + i*16 (wave-uniform base)
#define GLOAD_LDS(g, l)                                                                      \
    __builtin_amdgcn_global_load_lds((const __attribute__((address_space(1))) unsigned int*)(g), \
                                     (__attribute__((address_space(3))) unsigned int*)(l), 16, 0, 0)
// counted waits + raw barrier (T3/T4)
#define WAITV(N) asm volatile("s_waitcnt vmcnt(" #N ")" ::: "memory")
#define WAITL0() asm volatile("s_waitcnt lgkmcnt(0)" ::: "memory")
#define BAR() __builtin_amdgcn_s_barrier()
#define PIN() __builtin_amdgcn_sched_barrier(0)

constexpr int TT = 128;    // sequence length
constexpr int CD = 384;    // n_emb
constexpr int HS = 64;     // head size
constexpr int GRID = 256;  // persistent: each block handles batches b + 256*it, it=0..3
constexpr int XCHUNK = 32 * CD * 4;  // 49152 B: 32 full rows, CONTIGUOUS in HBM

// ---- LDS layout ----
// x double-buffer: two 48 KB row-chunks (32 rows x 1536 B), XOR-swizzled 16B groups per row
constexpr int XB0 = 0, XB1 = XCHUNK;           // bytes
constexpr int OVB = 2 * XCHUNK;                // overlay base: 98304 B
// overlay (bf16 element indices), same strides as the proven round-3 kernel
constexpr int QK_STR = 72;
constexpr int VT_STR = 136;
constexpr int QS_OFF = OVB / 2;                         // 49152 elems
constexpr int KS_OFF = QS_OFF + TT * QK_STR;            // +9216
constexpr int VT_OFF = QS_OFF + 2 * TT * QK_STR;        // +18432
constexpr int PS_OFF = QS_OFF;                          // P overlays q/k after phase 2
constexpr int SMEM_BYTES = OVB + 2 * (2 * TT * QK_STR + 64 * VT_STR);  // 152576 <= 163840

// ---- pre-kernel: weights -> bf16 fragments in CHUNK-MAJOR order (unchanged, proven) ----
// frag f = (kki*3 + proj)*4 + nt ; wf[f*512 + lane*8 + j] = W_proj[16nt + (lane&15)][32kki + 8(lane>>4) + j]
__global__ void wconv_kernel(const float* __restrict__ wq, const float* __restrict__ wk,
                             const float* __restrict__ wv, bf16_t* __restrict__ wf) {
    const int t = blockIdx.x * 256 + threadIdx.x;
    if (t >= 144 * 64) return;
    const int lane = t & 63;
    const int f    = t >> 6;
    const int nt   = f & 3;
    const int proj = (f >> 2) % 3;
    const int kki  = f / 12;
    const float* W = (proj == 0) ? wq : ((proj == 1) ? wk : wv);
    const int h = 16 * nt + (lane & 15);
    const int c = 32 * kki + 8 * (lane >> 4);
    const float* src = W + h * CD + c;
    bf16x8 o;
#pragma unroll
    for (int j = 0; j < 8; ++j) o[j] = (bf16_t)src[j];
    *(bf16x8*)(wf + (size_t)t * 8) = o;
}

// ---- fused attention: 8 waves, W in registers, contiguous 48 KB row-chunk staging ----
__launch_bounds__(512, 2)
__global__ void attn_kernel(const float* __restrict__ x, const bf16_t* __restrict__ wf,
                            float* __restrict__ out) {
    __shared__ __align__(16) char smem_raw[SMEM_BYTES];
    bf16_t* smem = (bf16_t*)smem_raw;
    const int lane = threadIdx.x & 63;
    const int w    = threadIdx.x >> 6;  // 0..7
    const int l15  = lane & 15;
    const int g    = lane >> 4;         // 0..3
    const int cg   = w >> 1;            // h-tile group 0..3 (phase 1)
    const int mh   = w & 1;             // m-half within 32-row chunk (phase 1)
    const char* wfb = (const char*)wf;

    // ---- W fragments in registers: 3 proj x 12 ksteps x 4 VGPR = 144 VGPRs, loaded ONCE ----
    bf16x8 wreg[36];
#pragma unroll
    for (int kk = 0; kk < 12; ++kk)
#pragma unroll
        for (int pj = 0; pj < 3; ++pj)
            wreg[kk * 3 + pj] =
                *(const bf16x8*)(wfb + ((size_t)((kk * 3 + pj) * 4 + cg) << 10) + lane * 16);

    // ---- per-lane staging source map (once): 48 windows of 1024 B, wave w owns i = w*6+t ----
    // LDS byte L = i*1024 + lane*16 -> row r = L/1536, group gL = (L%1536)/16;
    // source group = gL ^ (r&7)  (XOR swizzle via pre-swizzled GLOBAL source; LDS dest stays linear)
    unsigned soff[6];
#pragma unroll
    for (int t = 0; t < 6; ++t) {
        unsigned L  = (unsigned)(w * 6 + t) * 1024u + (unsigned)lane * 16u;
        unsigned r  = L / 1536u;
        unsigned gL = (L - r * 1536u) >> 4;
        soff[t] = r * 1536u + ((gL ^ (r & 7u)) << 4);
    }
    auto stage = [&](const char* gsrc, char* lds) {  // 6 loads per wave, uniform
#pragma unroll
        for (int t = 0; t < 6; ++t) GLOAD_LDS(gsrc + soff[t], lds + (w * 6 + t) * 1024);
    };

    // ---- phase-1 x read address (swizzled): row R = 16*mh + l15, kstep kk -> groups 8kk+2g, +1 ----
    const int      R   = 16 * mh + l15;
    const unsigned xro = (unsigned)R * 1536u + (unsigned)(((2 * g) ^ (R & 7)) << 4);

    auto compute_chunk = [&](int c, const char* xs) {
        floatx4 acc0 = (floatx4)0.0f, acc1 = (floatx4)0.0f, acc2 = (floatx4)0.0f;
#pragma unroll
        for (int kk = 0; kk < 12; ++kk) {
            const unsigned a0 = xro + 128u * kk;
            float4 f0 = *(const float4*)(xs + a0);
            float4 f1 = *(const float4*)(xs + (a0 ^ 16u));
            bf16x8 a;
            a[0] = (bf16_t)f0.x; a[1] = (bf16_t)f0.y; a[2] = (bf16_t)f0.z; a[3] = (bf16_t)f0.w;
            a[4] = (bf16_t)f1.x; a[5] = (bf16_t)f1.y; a[6] = (bf16_t)f1.z; a[7] = (bf16_t)f1.w;
            acc0 = MFMA16(a, wreg[kk * 3 + 0], acc0);
            acc1 = MFMA16(a, wreg[kk * 3 + 1], acc1);
            acc2 = MFMA16(a, wreg[kk * 3 + 2], acc2);
        }
        // write q,k as [t][h] and v transposed [h][t] into the overlay
        const int t0 = 32 * c + 16 * mh + 4 * g;
        const int h  = 16 * cg + l15;
#pragma unroll
        for (int ri = 0; ri < 4; ++ri) {
            smem[QS_OFF + (t0 + ri) * QK_STR + h] = (bf16_t)acc0[ri];
            smem[KS_OFF + (t0 + ri) * QK_STR + h] = (bf16_t)acc1[ri];
            smem[VT_OFF + h * VT_STR + (t0 + ri)] = (bf16_t)acc2[ri];
        }
    };

    const char* xbase = (const char*)x;
    const char* xb00  = xbase + (size_t)blockIdx.x * TT * CD * 4;

    // prologue: batch 0 chunks 0,1 (PIN keeps the two 6-load groups FIFO-ordered)
    stage(xb00, smem_raw + XB0);
    PIN();
    stage(xb00 + XCHUNK, smem_raw + XB1);

#pragma unroll 1
    for (int it = 0; it < 4; ++it) {
        const int   b  = blockIdx.x + GRID * it;
        const char* xb = xbase + (size_t)b * TT * CD * 4;
        const char* xn = xb + (size_t)GRID * TT * CD * 4;  // next batch (unused at it==3)

        // FIFO on entry: it==0: [c0(6), c1(6)] ; it>0: [nc0(6), stores, nc1(6)]
        WAITV(6); BAR();                 // chunk 0 resident; newest 6 (c1) stay in flight
        compute_chunk(0, smem_raw + XB0);
        WAITL0(); BAR();                 // all waves done reading XB0 + overlay writes retired
        stage(xb + 2 * XCHUNK, smem_raw + XB0);
        WAITV(6); BAR();                 // chunk 1 resident (c2 in flight)
        compute_chunk(1, smem_raw + XB1);
        WAITL0(); BAR();
        stage(xb + 3 * XCHUNK, smem_raw + XB1);
        WAITV(6); BAR();                 // chunk 2 resident (c3 in flight)
        compute_chunk(2, smem_raw + XB0);
        WAITL0(); BAR();
        if (it < 3) {
            stage(xn, smem_raw + XB0);   // next batch chunk 0 -> streams through the epilogue
            WAITV(6);                    // chunk 3 resident (nc0 in flight)
        } else {
            WAITV(0);                    // tail: chunk 3 resident
        }
        BAR();
        compute_chunk(3, smem_raw + XB1);
        WAITL0(); BAR();                 // full q/k/vt overlay visible to all waves

        // ================= Phase 2: S = q k^T (wave w owns rows 16w..16w+15) =================
        floatx4 sacc[8];
#pragma unroll
        for (int nt = 0; nt < 8; ++nt) sacc[nt] = (floatx4)0.0f;
#pragma unroll
        for (int kt = 0; kt < 2; ++kt) {
            const int hh = 32 * kt + 8 * g;
            bf16x8 aq = *(const bf16x8*)(smem + QS_OFF + (16 * w + l15) * QK_STR + hh);
#pragma unroll
            for (int nt = 0; nt < 8; ++nt) {
                if (nt <= w) {  // causal: tile needed iff 16nt <= 16w+15
                    bf16x8 bk = *(const bf16x8*)(smem + KS_OFF + (16 * nt + l15) * QK_STR + hh);
                    sacc[nt] = MFMA16(aq, bk, sacc[nt]);
                }
            }
        }
        WAITL0(); BAR();                 // q/k reads retired before P overlays them

        // ================= causal mask + softmax, P -> LDS bf16 (full 128-wide rows) =========
        const float scale = 0.05103103630798287f;  // 384^-0.5
#pragma unroll
        for (int r = 0; r < 4; ++r) {
            const int t = 16 * w + 4 * g + r;
            float vals[8];
            float vmax = -__builtin_inff();
#pragma unroll
            for (int nt = 0; nt < 8; ++nt) {
                const int s = 16 * nt + l15;
                float v = (s <= t) ? sacc[nt][r] * scale : -__builtin_inff();
                vals[nt] = v;
                vmax = fmaxf(vmax, v);
            }
            vmax = fmaxf(vmax, __shfl_xor(vmax, 1));
            vmax = fmaxf(vmax, __shfl_xor(vmax, 2));
            vmax = fmaxf(vmax, __shfl_xor(vmax, 4));
            vmax = fmaxf(vmax, __shfl_xor(vmax, 8));
            float sum = 0.0f;
#pragma unroll
            for (int nt = 0; nt < 8; ++nt) {
                float e = __expf(vals[nt] - vmax);  // exp(-inf)=0 for masked / nt>w tiles
                vals[nt] = e;
                sum += e;
            }
            sum += __shfl_xor(sum, 1);
            sum += __shfl_xor(sum, 2);
            sum += __shfl_xor(sum, 4);
            sum += __shfl_xor(sum, 8);
            const float inv = 1.0f / sum;
#pragma unroll
            for (int nt = 0; nt < 8; ++nt)  // store all 8 tiles: zeros past the causal edge
                smem[PS_OFF + t * VT_STR + 16 * nt + l15] = (bf16_t)(vals[nt] * inv);
        }
        // no sync: each wave reads back only its own P rows

        // ================= O = P v =================
        floatx4 oacc[4];
#pragma unroll
        for (int nt = 0; nt < 4; ++nt) oacc[nt] = (floatx4)0.0f;
#pragma unroll
        for (int st = 0; st < 4; ++st) {
            if (st <= (w >> 1)) {  // s-chunks up to the causal edge (P holds zeros beyond t)
                const int ss = 32 * st + 8 * g;
                bf16x8 ap = *(const bf16x8*)(smem + PS_OFF + (16 * w + l15) * VT_STR + ss);
#pragma unroll
                for (int nt = 0; nt < 4; ++nt) {
                    bf16x8 bv = *(const bf16x8*)(smem + VT_OFF + (16 * nt + l15) * VT_STR + ss);
                    oacc[nt] = MFMA16(ap, bv, oacc[nt]);
                }
            }
        }

        float* ob = out + (size_t)b * TT * HS;
#pragma unroll
        for (int nt = 0; nt < 4; ++nt)
#pragma unroll
            for (int r = 0; r < 4; ++r)
                ob[(size_t)(16 * w + 4 * g + r) * HS + 16 * nt + l15] = oacc[nt][r];

        // next batch chunk 1 at epilogue end: loop-top WAITV(6) leaves exactly these 6 in flight
        if (it < 3) {
            PIN();  // keep stores (and nc0) older than nc1 in the vmem FIFO
            stage(xn + XCHUNK, smem_raw + XB1);
        }
    }
}

extern "C" void kernel_launch(void* const* d_in, const int* in_sizes, int n_in,
                              void* d_out, int out_size, void* d_ws, size_t ws_size,
                              hipStream_t stream) {
    // setup_inputs order: x, Wk, Wq, Wv
    const float* x  = (const float*)d_in[0];
    const float* wk = (const float*)d_in[1];
    const float* wq = (const float*)d_in[2];
    const float* wv = (const float*)d_in[3];
    float* out = (float*)d_out;

    bf16_t* wf = (bf16_t*)d_ws;  // chunk-major weight fragments: 144 KB

    wconv_kernel<<<36, 256, 0, stream>>>(wq, wk, wv, wf);
    attn_kernel<<<GRID, 512, 0, stream>>>(x, wf, out);
}

// Round 3
// 429.458 us; speedup vs baseline: 1.0026x; 1.0026x over previous
//
#include <hip/hip_runtime.h>

typedef __bf16 bf16_t;
typedef __attribute__((ext_vector_type(8))) __bf16 bf16x8;
typedef __attribute__((ext_vector_type(4))) float floatx4;

#define MFMA16(a, b, c) __builtin_amdgcn_mfma_f32_16x16x32_bf16((a), (b), (c), 0, 0, 0)
// async global->LDS, 16B/lane: lane i's 16B lands at ldsbase + i*16 (wave-uniform base)
#define GLOAD_LDS(g, l)                                                                      \
    __builtin_amdgcn_global_load_lds((const __attribute__((address_space(1))) unsigned int*)(g), \
                                     (__attribute__((address_space(3))) unsigned int*)(l), 16, 0, 0)
// counted waits + raw barrier (T3/T4)
#define WAITV(N) asm volatile("s_waitcnt vmcnt(" #N ")" ::: "memory")
#define WAITL0() asm volatile("s_waitcnt lgkmcnt(0)" ::: "memory")
#define BAR() __builtin_amdgcn_s_barrier()
#define PIN() __builtin_amdgcn_sched_barrier(0)

constexpr int TT = 128;    // sequence length
constexpr int CD = 384;    // n_emb
constexpr int HS = 64;     // head size
constexpr int GRID = 256;  // persistent: each block handles batches b + 256*it, it=0..3
constexpr int XCHUNK = 32 * CD * 4;  // 49152 B: 32 full rows, CONTIGUOUS in HBM

// ---- LDS layout ----
// x double-buffer: two 48 KB row-chunks (32 rows x 1536 B), XOR-swizzled 16B groups per row
constexpr int XB0 = 0, XB1 = XCHUNK;           // bytes
constexpr int OVB = 2 * XCHUNK;                // overlay base: 98304 B
// overlay (bf16 element indices), same strides as the proven round-3 kernel
constexpr int QK_STR = 72;
constexpr int VT_STR = 136;
constexpr int QS_OFF = OVB / 2;                         // 49152 elems
constexpr int KS_OFF = QS_OFF + TT * QK_STR;            // +9216
constexpr int VT_OFF = QS_OFF + 2 * TT * QK_STR;        // +18432
constexpr int PS_OFF = QS_OFF;                          // P overlays q/k after phase 2
constexpr int SMEM_BYTES = OVB + 2 * (2 * TT * QK_STR + 64 * VT_STR);  // 152576 <= 163840

// ---- pre-kernel: weights -> bf16 fragments in CHUNK-MAJOR order (unchanged, proven) ----
// frag f = (kki*3 + proj)*4 + nt ; wf[f*512 + lane*8 + j] = W_proj[16nt + (lane&15)][32kki + 8(lane>>4) + j]
__global__ void wconv_kernel(const float* __restrict__ wq, const float* __restrict__ wk,
                             const float* __restrict__ wv, bf16_t* __restrict__ wf) {
    const int t = blockIdx.x * 256 + threadIdx.x;
    if (t >= 144 * 64) return;
    const int lane = t & 63;
    const int f    = t >> 6;
    const int nt   = f & 3;
    const int proj = (f >> 2) % 3;
    const int kki  = f / 12;
    const float* W = (proj == 0) ? wq : ((proj == 1) ? wk : wv);
    const int h = 16 * nt + (lane & 15);
    const int c = 32 * kki + 8 * (lane >> 4);
    const float* src = W + h * CD + c;
    bf16x8 o;
#pragma unroll
    for (int j = 0; j < 8; ++j) o[j] = (bf16_t)src[j];
    *(bf16x8*)(wf + (size_t)t * 8) = o;
}

// ---- fused attention: 8 waves, W in registers, contiguous 48 KB row-chunk staging ----
// launch_bounds(512, 1): LDS (152.6 KB) already limits us to 1 block/CU, so allow the full
// 256-VGPR/wave budget — round-1's (512,2) capped at 128 VGPRs and spilled wreg[] to scratch
// (FETCH +152 MB, WRITE +77 MB, MfmaUtil 3.7%).
__launch_bounds__(512, 1)
__global__ void attn_kernel(const float* __restrict__ x, const bf16_t* __restrict__ wf,
                            float* __restrict__ out) {
    __shared__ __align__(16) char smem_raw[SMEM_BYTES];
    bf16_t* smem = (bf16_t*)smem_raw;
    const int lane = threadIdx.x & 63;
    const int w    = threadIdx.x >> 6;  // 0..7
    const int l15  = lane & 15;
    const int g    = lane >> 4;         // 0..3
    const int cg   = w >> 1;            // h-tile group 0..3 (phase 1)
    const int mh   = w & 1;             // m-half within 32-row chunk (phase 1)
    const char* wfb = (const char*)wf;

    // ---- W fragments in registers: 3 proj x 12 ksteps x 4 VGPR = 144 VGPRs, loaded ONCE ----
    bf16x8 wreg[36];
#pragma unroll
    for (int kk = 0; kk < 12; ++kk)
#pragma unroll
        for (int pj = 0; pj < 3; ++pj)
            wreg[kk * 3 + pj] =
                *(const bf16x8*)(wfb + ((size_t)((kk * 3 + pj) * 4 + cg) << 10) + lane * 16);

    // ---- per-lane staging source map (once): 48 windows of 1024 B, wave w owns i = w*6+t ----
    // LDS byte L = i*1024 + lane*16 -> row r = L/1536, group gL = (L%1536)/16;
    // source group = gL ^ (r&7)  (XOR swizzle via pre-swizzled GLOBAL source; LDS dest stays linear)
    unsigned soff[6];
#pragma unroll
    for (int t = 0; t < 6; ++t) {
        unsigned L  = (unsigned)(w * 6 + t) * 1024u + (unsigned)lane * 16u;
        unsigned r  = L / 1536u;
        unsigned gL = (L - r * 1536u) >> 4;
        soff[t] = r * 1536u + ((gL ^ (r & 7u)) << 4);
    }
    auto stage = [&](const char* gsrc, char* lds) {  // 6 loads per wave, uniform
#pragma unroll
        for (int t = 0; t < 6; ++t) GLOAD_LDS(gsrc + soff[t], lds + (w * 6 + t) * 1024);
    };

    // ---- phase-1 x read address (swizzled): row R = 16*mh + l15, kstep kk -> groups 8kk+2g, +1 ----
    const int      R   = 16 * mh + l15;
    const unsigned xro = (unsigned)R * 1536u + (unsigned)(((2 * g) ^ (R & 7)) << 4);

    auto compute_chunk = [&](int c, const char* xs) {
        floatx4 acc0 = (floatx4)0.0f, acc1 = (floatx4)0.0f, acc2 = (floatx4)0.0f;
#pragma unroll
        for (int kk = 0; kk < 12; ++kk) {
            const unsigned a0 = xro + 128u * kk;
            float4 f0 = *(const float4*)(xs + a0);
            float4 f1 = *(const float4*)(xs + (a0 ^ 16u));
            bf16x8 a;
            a[0] = (bf16_t)f0.x; a[1] = (bf16_t)f0.y; a[2] = (bf16_t)f0.z; a[3] = (bf16_t)f0.w;
            a[4] = (bf16_t)f1.x; a[5] = (bf16_t)f1.y; a[6] = (bf16_t)f1.z; a[7] = (bf16_t)f1.w;
            acc0 = MFMA16(a, wreg[kk * 3 + 0], acc0);
            acc1 = MFMA16(a, wreg[kk * 3 + 1], acc1);
            acc2 = MFMA16(a, wreg[kk * 3 + 2], acc2);
        }
        // write q,k as [t][h] and v transposed [h][t] into the overlay
        const int t0 = 32 * c + 16 * mh + 4 * g;
        const int h  = 16 * cg + l15;
#pragma unroll
        for (int ri = 0; ri < 4; ++ri) {
            smem[QS_OFF + (t0 + ri) * QK_STR + h] = (bf16_t)acc0[ri];
            smem[KS_OFF + (t0 + ri) * QK_STR + h] = (bf16_t)acc1[ri];
            smem[VT_OFF + h * VT_STR + (t0 + ri)] = (bf16_t)acc2[ri];
        }
    };

    const char* xbase = (const char*)x;
    const char* xb00  = xbase + (size_t)blockIdx.x * TT * CD * 4;

    // prologue: batch 0 chunks 0,1 (PIN keeps the two 6-load groups FIFO-ordered)
    stage(xb00, smem_raw + XB0);
    PIN();
    stage(xb00 + XCHUNK, smem_raw + XB1);

#pragma unroll 1
    for (int it = 0; it < 4; ++it) {
        const int   b  = blockIdx.x + GRID * it;
        const char* xb = xbase + (size_t)b * TT * CD * 4;
        const char* xn = xb + (size_t)GRID * TT * CD * 4;  // next batch (unused at it==3)

        // FIFO on entry: it==0: [c0(6), c1(6)] ; it>0: [nc0(6), stores, nc1(6)]
        WAITV(6); BAR();                 // chunk 0 resident; newest 6 (c1) stay in flight
        compute_chunk(0, smem_raw + XB0);
        WAITL0(); BAR();                 // all waves done reading XB0 + overlay writes retired
        stage(xb + 2 * XCHUNK, smem_raw + XB0);
        WAITV(6); BAR();                 // chunk 1 resident (c2 in flight)
        compute_chunk(1, smem_raw + XB1);
        WAITL0(); BAR();
        stage(xb + 3 * XCHUNK, smem_raw + XB1);
        WAITV(6); BAR();                 // chunk 2 resident (c3 in flight)
        compute_chunk(2, smem_raw + XB0);
        WAITL0(); BAR();
        if (it < 3) {
            stage(xn, smem_raw + XB0);   // next batch chunk 0 -> streams through the epilogue
            WAITV(6);                    // chunk 3 resident (nc0 in flight)
        } else {
            WAITV(0);                    // tail: chunk 3 resident
        }
        BAR();
        compute_chunk(3, smem_raw + XB1);
        WAITL0(); BAR();                 // full q/k/vt overlay visible to all waves

        // ================= Phase 2: S = q k^T (wave w owns rows 16w..16w+15) =================
        floatx4 sacc[8];
#pragma unroll
        for (int nt = 0; nt < 8; ++nt) sacc[nt] = (floatx4)0.0f;
#pragma unroll
        for (int kt = 0; kt < 2; ++kt) {
            const int hh = 32 * kt + 8 * g;
            bf16x8 aq = *(const bf16x8*)(smem + QS_OFF + (16 * w + l15) * QK_STR + hh);
#pragma unroll
            for (int nt = 0; nt < 8; ++nt) {
                if (nt <= w) {  // causal: tile needed iff 16nt <= 16w+15
                    bf16x8 bk = *(const bf16x8*)(smem + KS_OFF + (16 * nt + l15) * QK_STR + hh);
                    sacc[nt] = MFMA16(aq, bk, sacc[nt]);
                }
            }
        }
        WAITL0(); BAR();                 // q/k reads retired before P overlays them

        // ================= causal mask + softmax, P -> LDS bf16 (full 128-wide rows) =========
        const float scale = 0.05103103630798287f;  // 384^-0.5
#pragma unroll
        for (int r = 0; r < 4; ++r) {
            const int t = 16 * w + 4 * g + r;
            float vals[8];
            float vmax = -__builtin_inff();
#pragma unroll
            for (int nt = 0; nt < 8; ++nt) {
                const int s = 16 * nt + l15;
                float v = (s <= t) ? sacc[nt][r] * scale : -__builtin_inff();
                vals[nt] = v;
                vmax = fmaxf(vmax, v);
            }
            vmax = fmaxf(vmax, __shfl_xor(vmax, 1));
            vmax = fmaxf(vmax, __shfl_xor(vmax, 2));
            vmax = fmaxf(vmax, __shfl_xor(vmax, 4));
            vmax = fmaxf(vmax, __shfl_xor(vmax, 8));
            float sum = 0.0f;
#pragma unroll
            for (int nt = 0; nt < 8; ++nt) {
                float e = __expf(vals[nt] - vmax);  // exp(-inf)=0 for masked / nt>w tiles
                vals[nt] = e;
                sum += e;
            }
            sum += __shfl_xor(sum, 1);
            sum += __shfl_xor(sum, 2);
            sum += __shfl_xor(sum, 4);
            sum += __shfl_xor(sum, 8);
            const float inv = 1.0f / sum;
#pragma unroll
            for (int nt = 0; nt < 8; ++nt)  // store all 8 tiles: zeros past the causal edge
                smem[PS_OFF + t * VT_STR + 16 * nt + l15] = (bf16_t)(vals[nt] * inv);
        }
        // no sync: each wave reads back only its own P rows

        // ================= O = P v =================
        floatx4 oacc[4];
#pragma unroll
        for (int nt = 0; nt < 4; ++nt) oacc[nt] = (floatx4)0.0f;
#pragma unroll
        for (int st = 0; st < 4; ++st) {
            if (st <= (w >> 1)) {  // s-chunks up to the causal edge (P holds zeros beyond t)
                const int ss = 32 * st + 8 * g;
                bf16x8 ap = *(const bf16x8*)(smem + PS_OFF + (16 * w + l15) * VT_STR + ss);
#pragma unroll
                for (int nt = 0; nt < 4; ++nt) {
                    bf16x8 bv = *(const bf16x8*)(smem + VT_OFF + (16 * nt + l15) * VT_STR + ss);
                    oacc[nt] = MFMA16(ap, bv, oacc[nt]);
                }
            }
        }

        float* ob = out + (size_t)b * TT * HS;
#pragma unroll
        for (int nt = 0; nt < 4; ++nt)
#pragma unroll
            for (int r = 0; r < 4; ++r)
                ob[(size_t)(16 * w + 4 * g + r) * HS + 16 * nt + l15] = oacc[nt][r];

        // next batch chunk 1 at epilogue end: loop-top WAITV(6) leaves exactly these 6 in flight
        if (it < 3) {
            PIN();  // keep stores (and nc0) older than nc1 in the vmem FIFO
            stage(xn + XCHUNK, smem_raw + XB1);
        }
    }
}

extern "C" void kernel_launch(void* const* d_in, const int* in_sizes, int n_in,
                              void* d_out, int out_size, void* d_ws, size_t ws_size,
                              hipStream_t stream) {
    // setup_inputs order: x, Wk, Wq, Wv
    const float* x  = (const float*)d_in[0];
    const float* wk = (const float*)d_in[1];
    const float* wq = (const float*)d_in[2];
    const float* wv = (const float*)d_in[3];
    float* out = (float*)d_out;

    bf16_t* wf = (bf16_t*)d_ws;  // chunk-major weight fragments: 144 KB

    wconv_kernel<<<36, 256, 0, stream>>>(wq, wk, wv, wf);
    attn_kernel<<<GRID, 512, 0, stream>>>(x, wf, out);
}

// Round 4
// 323.446 us; speedup vs baseline: 1.3312x; 1.3278x over previous
//
#include <hip/hip_runtime.h>

typedef __bf16 bf16_t;
typedef __attribute__((ext_vector_type(8))) __bf16 bf16x8;
typedef __attribute__((ext_vector_type(4))) float floatx4;

#define MFMA16(a, b, c) __builtin_amdgcn_mfma_f32_16x16x32_bf16((a), (b), (c), 0, 0, 0)
// async global->LDS, 16B/lane: lane i's 16B lands at ldsbase + i*16 (wave-uniform base)
#define GLOAD_LDS(g, l)                                                                      \
    __builtin_amdgcn_global_load_lds((const __attribute__((address_space(1))) unsigned int*)(g), \
                                     (__attribute__((address_space(3))) unsigned int*)(l), 16, 0, 0)
// counted waits + raw barrier (T3/T4)
#define WAITV(N) asm volatile("s_waitcnt vmcnt(" #N ")" ::: "memory")
#define WAITL0() asm volatile("s_waitcnt lgkmcnt(0)" ::: "memory")
#define BAR() __builtin_amdgcn_s_barrier()
#define PIN() __builtin_amdgcn_sched_barrier(0)

constexpr int TT = 128;    // sequence length
constexpr int CD = 384;    // n_emb
constexpr int HS = 64;     // head size
constexpr int GRID = 256;  // persistent: each block handles batches b + 256*it, it=0..3
constexpr int XCHUNK = 32 * CD * 4;  // 49152 B: 32 full rows, CONTIGUOUS in HBM

// ---- LDS layout ----
// x double-buffer: two 48 KB row-chunks (32 rows x 1536 B), XOR-swizzled 16B groups per row
constexpr int XB0 = 0, XB1 = XCHUNK;           // bytes
constexpr int OVB = 2 * XCHUNK;                // overlay base: 98304 B
// overlay (bf16 element indices), proven strides
constexpr int QK_STR = 72;
constexpr int VT_STR = 136;
constexpr int QS_OFF = OVB / 2;                         // 49152 elems
constexpr int KS_OFF = QS_OFF + TT * QK_STR;            // +9216
constexpr int VT_OFF = QS_OFF + 2 * TT * QK_STR;        // +18432
constexpr int PS_OFF = QS_OFF;                          // P overlays q/k after phase 2
constexpr int SMEM_BYTES = OVB + 2 * (2 * TT * QK_STR + 64 * VT_STR);  // 152576 <= 163840

// ---- pre-kernel: weights -> bf16 fragments in CHUNK-MAJOR order (unchanged, proven) ----
// frag f = (kki*3 + proj)*4 + nt ; wf[f*512 + lane*8 + j] = W_proj[16nt + (lane&15)][32kki + 8(lane>>4) + j]
__global__ void wconv_kernel(const float* __restrict__ wq, const float* __restrict__ wk,
                             const float* __restrict__ wv, bf16_t* __restrict__ wf) {
    const int t = blockIdx.x * 256 + threadIdx.x;
    if (t >= 144 * 64) return;
    const int lane = t & 63;
    const int f    = t >> 6;
    const int nt   = f & 3;
    const int proj = (f >> 2) % 3;
    const int kki  = f / 12;
    const float* W = (proj == 0) ? wq : ((proj == 1) ? wk : wv);
    const int h = 16 * nt + (lane & 15);
    const int c = 32 * kki + 8 * (lane >> 4);
    const float* src = W + h * CD + c;
    bf16x8 o;
#pragma unroll
    for (int j = 0; j < 8; ++j) o[j] = (bf16_t)src[j];
    *(bf16x8*)(wf + (size_t)t * 8) = o;
}

// ---- fused attention: 4 waves (256 thr), W in registers, contiguous 48 KB row-chunk staging ----
// WHY 4 waves: an 8-wave WG at 1 WG/CU structurally forces 2 waves/EU -> 256-reg budget ->
// 128/128 arch/acc split -> wreg[36] (144 arch) spills (rounds 1-3: FETCH +152 MB, MfmaUtil 3.7%).
// 4 waves -> 1 wave/EU feasible -> 512 budget, arch cap 256: wreg fits. Phase 1 is HBM-bound
// (staging ~7.4 us/batch/CU vs ~1.3 us compute), so 1 wave/SIMD costs nothing there.
__launch_bounds__(256, 1)
__global__ void attn_kernel(const float* __restrict__ x, const bf16_t* __restrict__ wf,
                            float* __restrict__ out) {
    __shared__ __align__(16) char smem_raw[SMEM_BYTES];
    bf16_t* smem = (bf16_t*)smem_raw;
    const int lane = threadIdx.x & 63;
    const int w    = threadIdx.x >> 6;  // 0..3 ; wave w owns h-tile w in phase 1
    const int l15  = lane & 15;
    const int g    = lane >> 4;         // 0..3
    const char* wfb = (const char*)wf;

    // ---- W fragments in registers: 3 proj x 12 ksteps x 4 VGPR = 144 VGPRs, loaded ONCE ----
    bf16x8 wreg[36];
#pragma unroll
    for (int kk = 0; kk < 12; ++kk)
#pragma unroll
        for (int pj = 0; pj < 3; ++pj)
            wreg[kk * 3 + pj] =
                *(const bf16x8*)(wfb + ((size_t)((kk * 3 + pj) * 4 + w) << 10) + lane * 16);

    // ---- per-lane staging source map (once): 48 windows of 1024 B, wave w owns i = w*12+t ----
    // LDS byte L = i*1024 + lane*16 -> row r = L/1536, group gL = (L%1536)/16;
    // source group = gL ^ (r&7)  (XOR swizzle via pre-swizzled GLOBAL source; LDS dest stays linear)
    unsigned soff[12];
#pragma unroll
    for (int t = 0; t < 12; ++t) {
        unsigned L  = (unsigned)(w * 12 + t) * 1024u + (unsigned)lane * 16u;
        unsigned r  = L / 1536u;
        unsigned gL = (L - r * 1536u) >> 4;
        soff[t] = r * 1536u + ((gL ^ (r & 7u)) << 4);
    }
    auto stage = [&](const char* gsrc, char* lds) {  // 12 loads per wave, uniform
#pragma unroll
        for (int t = 0; t < 12; ++t) GLOAD_LDS(gsrc + soff[t], lds + (w * 12 + t) * 1024);
    };

    // ---- phase-1 x read addresses (swizzled): row R = 16*mt + l15, kstep kk -> groups 8kk+2g,+1 ----
    unsigned xro[2];
#pragma unroll
    for (int mt = 0; mt < 2; ++mt) {
        const int R = 16 * mt + l15;
        xro[mt] = (unsigned)R * 1536u + (unsigned)(((2 * g) ^ (R & 7)) << 4);
    }

    auto compute_chunk = [&](int c, const char* xs) {
        floatx4 acc[2][3];
#pragma unroll
        for (int mt = 0; mt < 2; ++mt)
#pragma unroll
            for (int pj = 0; pj < 3; ++pj) acc[mt][pj] = (floatx4)0.0f;
#pragma unroll
        for (int kk = 0; kk < 12; ++kk) {
#pragma unroll
            for (int mt = 0; mt < 2; ++mt) {
                const unsigned a0 = xro[mt] + 128u * kk;
                float4 f0 = *(const float4*)(xs + a0);
                float4 f1 = *(const float4*)(xs + (a0 ^ 16u));
                bf16x8 a;
                a[0] = (bf16_t)f0.x; a[1] = (bf16_t)f0.y; a[2] = (bf16_t)f0.z; a[3] = (bf16_t)f0.w;
                a[4] = (bf16_t)f1.x; a[5] = (bf16_t)f1.y; a[6] = (bf16_t)f1.z; a[7] = (bf16_t)f1.w;
                acc[mt][0] = MFMA16(a, wreg[kk * 3 + 0], acc[mt][0]);
                acc[mt][1] = MFMA16(a, wreg[kk * 3 + 1], acc[mt][1]);
                acc[mt][2] = MFMA16(a, wreg[kk * 3 + 2], acc[mt][2]);
            }
        }
        // write q,k as [t][h] and v transposed [h][t] into the overlay
        const int h = 16 * w + l15;
#pragma unroll
        for (int mt = 0; mt < 2; ++mt) {
            const int t0 = 32 * c + 16 * mt + 4 * g;
#pragma unroll
            for (int ri = 0; ri < 4; ++ri) {
                smem[QS_OFF + (t0 + ri) * QK_STR + h] = (bf16_t)acc[mt][0][ri];
                smem[KS_OFF + (t0 + ri) * QK_STR + h] = (bf16_t)acc[mt][1][ri];
                smem[VT_OFF + h * VT_STR + (t0 + ri)] = (bf16_t)acc[mt][2][ri];
            }
        }
    };

    const char* xbase = (const char*)x;
    const char* xb00  = xbase + (size_t)blockIdx.x * TT * CD * 4;

    // prologue: batch 0 chunks 0,1 (PIN keeps the two 12-load groups FIFO-ordered)
    stage(xb00, smem_raw + XB0);
    PIN();
    stage(xb00 + XCHUNK, smem_raw + XB1);

#pragma unroll 1
    for (int it = 0; it < 4; ++it) {
        const int   b  = blockIdx.x + GRID * it;
        const char* xb = xbase + (size_t)b * TT * CD * 4;
        const char* xn = xb + (size_t)GRID * TT * CD * 4;  // next batch (unused at it==3)

        // FIFO on entry: it==0: [c0(12), c1(12)] ; it>0: [nc0(12), stores, nc1(12)]
        WAITV(12); BAR();                // chunk 0 resident; newest 12 (c1) stay in flight
        compute_chunk(0, smem_raw + XB0);
        WAITL0(); BAR();                 // all waves done reading XB0 + overlay writes retired
        stage(xb + 2 * XCHUNK, smem_raw + XB0);
        WAITV(12); BAR();                // chunk 1 resident (c2 in flight)
        compute_chunk(1, smem_raw + XB1);
        WAITL0(); BAR();
        stage(xb + 3 * XCHUNK, smem_raw + XB1);
        WAITV(12); BAR();                // chunk 2 resident (c3 in flight)
        compute_chunk(2, smem_raw + XB0);
        WAITL0(); BAR();
        if (it < 3) {
            stage(xn, smem_raw + XB0);   // next batch chunk 0 -> streams through the epilogue
            WAITV(12);                   // chunk 3 resident (nc0 in flight)
        } else {
            WAITV(0);                    // tail: chunk 3 resident
        }
        BAR();
        compute_chunk(3, smem_raw + XB1);
        WAITL0(); BAR();                 // full q/k/vt overlay visible to all waves

        // ================= Phase 2: S = q k^T (wave w owns rows 32w..32w+31) =================
        floatx4 sacc[2][8];
#pragma unroll
        for (int mt = 0; mt < 2; ++mt)
#pragma unroll
            for (int nt = 0; nt < 8; ++nt) sacc[mt][nt] = (floatx4)0.0f;
#pragma unroll
        for (int kt = 0; kt < 2; ++kt) {
            const int hh = 32 * kt + 8 * g;
            bf16x8 aq[2];
            aq[0] = *(const bf16x8*)(smem + QS_OFF + (32 * w + l15) * QK_STR + hh);
            aq[1] = *(const bf16x8*)(smem + QS_OFF + (32 * w + 16 + l15) * QK_STR + hh);
#pragma unroll
            for (int nt = 0; nt < 8; ++nt) {
                if (16 * nt <= 32 * w + 31) {  // causal tile skip
                    bf16x8 bk = *(const bf16x8*)(smem + KS_OFF + (16 * nt + l15) * QK_STR + hh);
                    if (16 * nt <= 32 * w + 15) sacc[0][nt] = MFMA16(aq[0], bk, sacc[0][nt]);
                    sacc[1][nt] = MFMA16(aq[1], bk, sacc[1][nt]);
                }
            }
        }
        WAITL0(); BAR();                 // q/k reads retired before P overlays them

        // ================= causal mask + softmax, P -> LDS bf16 =================
        const float scale = 0.05103103630798287f;  // 384^-0.5
#pragma unroll
        for (int mt = 0; mt < 2; ++mt) {
#pragma unroll
            for (int r = 0; r < 4; ++r) {
                const int t = 32 * w + 16 * mt + 4 * g + r;
                float vals[8];
                float vmax = -__builtin_inff();
#pragma unroll
                for (int nt = 0; nt < 8; ++nt) {
                    const int s = 16 * nt + l15;
                    float v = (s <= t) ? sacc[mt][nt][r] * scale : -__builtin_inff();
                    vals[nt] = v;
                    vmax = fmaxf(vmax, v);
                }
                vmax = fmaxf(vmax, __shfl_xor(vmax, 1));
                vmax = fmaxf(vmax, __shfl_xor(vmax, 2));
                vmax = fmaxf(vmax, __shfl_xor(vmax, 4));
                vmax = fmaxf(vmax, __shfl_xor(vmax, 8));
                float sum = 0.0f;
#pragma unroll
                for (int nt = 0; nt < 8; ++nt) {
                    float e = __expf(vals[nt] - vmax);  // exp(-inf)=0 past the causal edge
                    vals[nt] = e;
                    sum += e;
                }
                sum += __shfl_xor(sum, 1);
                sum += __shfl_xor(sum, 2);
                sum += __shfl_xor(sum, 4);
                sum += __shfl_xor(sum, 8);
                const float inv = 1.0f / sum;
#pragma unroll
                for (int nt = 0; nt < 8; ++nt)
                    smem[PS_OFF + t * VT_STR + 16 * nt + l15] = (bf16_t)(vals[nt] * inv);
            }
        }
        // no sync: each wave reads back only its own P rows

        // ================= O = P v (skip all-zero s-chunks past the causal edge) =================
        floatx4 oacc[2][4];
#pragma unroll
        for (int mt = 0; mt < 2; ++mt)
#pragma unroll
            for (int nt = 0; nt < 4; ++nt) oacc[mt][nt] = (floatx4)0.0f;

        for (int st = 0; st <= w; ++st) {
            const int ss = 32 * st + 8 * g;
            bf16x8 ap0 = *(const bf16x8*)(smem + PS_OFF + (32 * w + l15) * VT_STR + ss);
            bf16x8 ap1 = *(const bf16x8*)(smem + PS_OFF + (32 * w + 16 + l15) * VT_STR + ss);
#pragma unroll
            for (int nt = 0; nt < 4; ++nt) {
                bf16x8 bv = *(const bf16x8*)(smem + VT_OFF + (16 * nt + l15) * VT_STR + ss);
                oacc[0][nt] = MFMA16(ap0, bv, oacc[0][nt]);
                oacc[1][nt] = MFMA16(ap1, bv, oacc[1][nt]);
            }
        }

        float* ob = out + (size_t)b * TT * HS;
#pragma unroll
        for (int mt = 0; mt < 2; ++mt)
#pragma unroll
            for (int nt = 0; nt < 4; ++nt) {
                const int t0 = 32 * w + 16 * mt + 4 * g;
                const int h  = 16 * nt + l15;
#pragma unroll
                for (int r = 0; r < 4; ++r)
                    ob[(size_t)(t0 + r) * HS + h] = oacc[mt][nt][r];
            }

        // next batch chunk 1 at epilogue end: loop-top WAITV(12) drains [nc0, stores], leaves nc1
        if (it < 3) {
            PIN();  // keep stores (and nc0) older than nc1 in the vmem FIFO
            stage(xn + XCHUNK, smem_raw + XB1);
        }
    }
}

extern "C" void kernel_launch(void* const* d_in, const int* in_sizes, int n_in,
                              void* d_out, int out_size, void* d_ws, size_t ws_size,
                              hipStream_t stream) {
    // setup_inputs order: x, Wk, Wq, Wv
    const float* x  = (const float*)d_in[0];
    const float* wk = (const float*)d_in[1];
    const float* wq = (const float*)d_in[2];
    const float* wv = (const float*)d_in[3];
    float* out = (float*)d_out;

    bf16_t* wf = (bf16_t*)d_ws;  // chunk-major weight fragments: 144 KB

    wconv_kernel<<<36, 256, 0, stream>>>(wq, wk, wv, wf);
    attn_kernel<<<GRID, 256, 0, stream>>>(x, wf, out);
}